// Round 2
// baseline (117.105 us; speedup 1.0000x reference)
//
#include <hip/hip_runtime.h>

// ConvertParamsLayerFrom0: B=2048, NH=128, NV=256
//   inv = rsqrt(covh_diag2)                     [B,NH]
//   wt2[b,h,v] = wt1[b,h,v] * inv[b,h]          [B,NH,NV]
//   b2[b,v]    = b1[b,v] - sum_h wt1[b,h,v] * (inv[b,h]*muh2[b,h])   [B,NV]
//
// Memory-bound: ~518 MiB traffic, floor ~86us @ 6.3 TB/s.

#define NB 2048
#define NH 128
#define NV 256

__global__ __launch_bounds__(256, 4) void convert_params_kernel(
    const float* __restrict__ b1,    // [B, NV]
    const float* __restrict__ wt1,   // [B, NH, NV]
    const float* __restrict__ muh2,  // [B, NH]
    const float* __restrict__ cov,   // [B, NH]
    float* __restrict__ b2,          // [B, NV]
    float* __restrict__ wt2)         // [B, NH, NV]
{
    const int b = blockIdx.x;
    const int t = threadIdx.x;

    __shared__ float s_inv[NH];      // rsqrt(cov)
    __shared__ float s_sm[NH];       // rsqrt(cov) * muh2
    __shared__ float s_red[4][NV];   // cross-h-group partial sums (4 KiB)

    // Stage per-(b,h) scalars in LDS.
    if (t < NH) {
        float c   = cov[(size_t)b * NH + t];
        float inv = rsqrtf(c);
        s_inv[t] = inv;
        s_sm[t]  = inv * muh2[(size_t)b * NH + t];
    }
    __syncthreads();

    // Layout: 4 h-groups x 64 lanes; each lane owns a float4 of v.
    const int lane = t & 63;         // 0..63  -> v4 = lane*4
    const int hg   = t >> 6;         // 0..3   -> h = hg, hg+4, hg+8, ...
    const int v4   = lane * 4;

    const float* wt1_b = wt1 + (size_t)b * NH * NV;
    float*       wt2_b = wt2 + (size_t)b * NH * NV;

    float ax = 0.f, ay = 0.f, az = 0.f, aw = 0.f;

    #pragma unroll 8
    for (int h = hg; h < NH; h += 4) {
        const float4 w = *reinterpret_cast<const float4*>(wt1_b + h * NV + v4);
        const float inv = s_inv[h];   // wave-uniform broadcast (free)
        const float sm  = s_sm[h];
        float4 o;
        o.x = w.x * inv; o.y = w.y * inv; o.z = w.z * inv; o.w = w.w * inv;
        *reinterpret_cast<float4*>(wt2_b + h * NV + v4) = o;
        ax = fmaf(w.x, sm, ax);
        ay = fmaf(w.y, sm, ay);
        az = fmaf(w.z, sm, az);
        aw = fmaf(w.w, sm, aw);
    }

    // Reduce the 4 h-group partials via LDS, then write b2 (wave 0 only).
    s_red[hg][v4 + 0] = ax;
    s_red[hg][v4 + 1] = ay;
    s_red[hg][v4 + 2] = az;
    s_red[hg][v4 + 3] = aw;
    __syncthreads();

    if (hg == 0) {
        // lane covers v4..v4+3
        #pragma unroll
        for (int j = 0; j < 4; ++j) {
            const int v = v4 + j;
            const float sum = s_red[0][v] + s_red[1][v] + s_red[2][v] + s_red[3][v];
            b2[(size_t)b * NV + v] = b1[(size_t)b * NV + v] - sum;
        }
    }
}

extern "C" void kernel_launch(void* const* d_in, const int* in_sizes, int n_in,
                              void* d_out, int out_size, void* d_ws, size_t ws_size,
                              hipStream_t stream) {
    const float* b1   = (const float*)d_in[0];  // [B, NV]
    const float* wt1  = (const float*)d_in[1];  // [B, NH, NV]
    const float* muh2 = (const float*)d_in[2];  // [B, NH]
    const float* cov  = (const float*)d_in[3];  // [B, NH]

    // d_out = concat(b2 [B*NV], wt2 [B*NH*NV]) in reference return order.
    float* b2  = (float*)d_out;
    float* wt2 = (float*)d_out + (size_t)NB * NV;

    convert_params_kernel<<<NB, 256, 0, stream>>>(b1, wt1, muh2, cov, b2, wt2);
}

// Round 4
// 113.727 us; speedup vs baseline: 1.0297x; 1.0297x over previous
//
#include <hip/hip_runtime.h>

// ConvertParamsLayerFrom0: B=2048, NH=128, NV=256
//   inv = rsqrt(covh_diag2)                     [B,NH]
//   wt2[b,h,v] = wt1[b,h,v] * inv[b,h]          [B,NH,NV]
//   b2[b,v]    = b1[b,v] - sum_h wt1[b,h,v] * (inv[b,h]*muh2[b,h])   [B,NV]
//
// Memory-bound: ~543 MB traffic, floor ~86us @ 6.3 TB/s mixed-stream.
// R3: R2 plan with clang ext_vector float4 (HIP_vector_type rejected by
//     the nontemporal builtins).

#define NB 2048
#define NH 128
#define NV 256

typedef float f32x4 __attribute__((ext_vector_type(4)));

__global__ __launch_bounds__(256, 4) void convert_params_kernel(
    const float* __restrict__ b1,    // [B, NV]
    const float* __restrict__ wt1,   // [B, NH, NV]
    const float* __restrict__ muh2,  // [B, NH]
    const float* __restrict__ cov,   // [B, NH]
    float* __restrict__ b2,          // [B, NV]
    float* __restrict__ wt2)         // [B, NH, NV]
{
    const int b = blockIdx.x;
    const int t = threadIdx.x;

    __shared__ float s_inv[NH];      // rsqrt(cov)
    __shared__ float s_sm[NH];       // rsqrt(cov) * muh2
    __shared__ float s_red[4][NV];   // cross-h-group partials (4 KiB)

    // Preload b1 (1 elem/thread, coalesced) — latency hides under main loop.
    const float b1v = b1[(size_t)b * NV + t];

    // Stage per-(b,h) scalars in LDS.
    if (t < NH) {
        float c   = cov[(size_t)b * NH + t];
        float inv = rsqrtf(c);
        s_inv[t] = inv;
        s_sm[t]  = inv * muh2[(size_t)b * NH + t];
    }
    __syncthreads();

    // Layout: 4 h-groups x 64 lanes; each lane owns a float4 of v.
    const int lane = t & 63;         // 0..63  -> v4 = lane*4
    const int hg   = t >> 6;         // 0..3   -> h = hg + 4k
    const int v4   = lane * 4;

    const float* wt1_b = wt1 + (size_t)b * NH * NV + v4;
    float*       wt2_b = wt2 + (size_t)b * NH * NV + v4;

    float ax = 0.f, ay = 0.f, az = 0.f, aw = 0.f;

    // 32 h-rows per lane, processed as 8 groups of 4 independent loads so
    // 4 loads are outstanding before the first dependent use (vmcnt(3)).
    #pragma unroll
    for (int g = 0; g < 8; ++g) {
        const int h0 = hg + g * 16;                 // rows h0, h0+4, h0+8, h0+12
        const f32x4 w0 = __builtin_nontemporal_load(
            reinterpret_cast<const f32x4*>(wt1_b + (h0 +  0) * NV));
        const f32x4 w1 = __builtin_nontemporal_load(
            reinterpret_cast<const f32x4*>(wt1_b + (h0 +  4) * NV));
        const f32x4 w2 = __builtin_nontemporal_load(
            reinterpret_cast<const f32x4*>(wt1_b + (h0 +  8) * NV));
        const f32x4 w3 = __builtin_nontemporal_load(
            reinterpret_cast<const f32x4*>(wt1_b + (h0 + 12) * NV));

        #pragma unroll
        for (int j = 0; j < 4; ++j) {
            const f32x4 w = (j == 0) ? w0 : (j == 1) ? w1 : (j == 2) ? w2 : w3;
            const int h = h0 + j * 4;
            const float inv = s_inv[h];             // wave-uniform broadcast
            const float sm  = s_sm[h];
            const f32x4 o = w * inv;
            __builtin_nontemporal_store(o,
                reinterpret_cast<f32x4*>(wt2_b + h * NV));
            ax = fmaf(w.x, sm, ax);
            ay = fmaf(w.y, sm, ay);
            az = fmaf(w.z, sm, az);
            aw = fmaf(w.w, sm, aw);
        }
    }

    // Reduce the 4 h-group partials via LDS; all 256 threads write one v each.
    s_red[hg][v4 + 0] = ax;
    s_red[hg][v4 + 1] = ay;
    s_red[hg][v4 + 2] = az;
    s_red[hg][v4 + 3] = aw;
    __syncthreads();

    const float sum = s_red[0][t] + s_red[1][t] + s_red[2][t] + s_red[3][t];
    b2[(size_t)b * NV + t] = b1v - sum;
}

extern "C" void kernel_launch(void* const* d_in, const int* in_sizes, int n_in,
                              void* d_out, int out_size, void* d_ws, size_t ws_size,
                              hipStream_t stream) {
    const float* b1   = (const float*)d_in[0];  // [B, NV]
    const float* wt1  = (const float*)d_in[1];  // [B, NH, NV]
    const float* muh2 = (const float*)d_in[2];  // [B, NH]
    const float* cov  = (const float*)d_in[3];  // [B, NH]

    // d_out = concat(b2 [B*NV], wt2 [B*NH*NV]) in reference return order.
    float* b2  = (float*)d_out;
    float* wt2 = (float*)d_out + (size_t)NB * NV;

    convert_params_kernel<<<NB, 256, 0, stream>>>(b1, wt1, muh2, cov, b2, wt2);
}

// Round 5
// 93.641 us; speedup vs baseline: 1.2506x; 1.2145x over previous
//
#include <hip/hip_runtime.h>

// ConvertParamsLayerFrom0: B=2048, NH=128, NV=256
//   inv = rsqrt(covh_diag2)                     [B,NH]
//   wt2[b,h,v] = wt1[b,h,v] * inv[b,h]          [B,NH,NV]
//   b2[b,v]    = b1[b,v] - sum_h wt1[b,h,v] * (inv[b,h]*muh2[b,h])   [B,NV]
//
// R4 theory: wt1 (268 MB) ~= L3 (256 MiB). Cached loads + nt stores keep wt1
// L3-resident across graph replays -> HBM carries only the write stream.
// Loads: normal (cacheable). Stores: nontemporal (don't evict wt1 from L3).

#define NB 2048
#define NH 128
#define NV 256

typedef float f32x4 __attribute__((ext_vector_type(4)));

__global__ __launch_bounds__(256, 4) void convert_params_kernel(
    const float* __restrict__ b1,    // [B, NV]
    const float* __restrict__ wt1,   // [B, NH, NV]
    const float* __restrict__ muh2,  // [B, NH]
    const float* __restrict__ cov,   // [B, NH]
    float* __restrict__ b2,          // [B, NV]
    float* __restrict__ wt2)         // [B, NH, NV]
{
    const int b = blockIdx.x;
    const int t = threadIdx.x;

    __shared__ float s_inv[NH];      // rsqrt(cov)
    __shared__ float s_sm[NH];       // rsqrt(cov) * muh2
    __shared__ float s_red[4][NV];   // cross-h-group partials (4 KiB)

    // Preload b1 (1 elem/thread, coalesced) — hides under main loop.
    const float b1v = b1[(size_t)b * NV + t];

    // Stage per-(b,h) scalars in LDS.
    if (t < NH) {
        float c   = cov[(size_t)b * NH + t];
        float inv = rsqrtf(c);
        s_inv[t] = inv;
        s_sm[t]  = inv * muh2[(size_t)b * NH + t];
    }
    __syncthreads();

    // Layout: 4 h-groups x 64 lanes; each lane owns a float4 of v.
    const int lane = t & 63;         // 0..63  -> v4 = lane*4
    const int hg   = t >> 6;         // 0..3
    const int v4   = lane * 4;

    const float* wt1_b = wt1 + (size_t)b * NH * NV + v4;
    float*       wt2_b = wt2 + (size_t)b * NH * NV + v4;

    float ax = 0.f, ay = 0.f, az = 0.f, aw = 0.f;

    // 32 h-rows per lane: 4 groups of 8 outstanding cacheable loads.
    // Within a group the block sweeps 32 contiguous rows (32 KiB).
    #pragma unroll
    for (int g = 0; g < 4; ++g) {
        const int hbase = hg + 32 * g;            // rows hbase + 4j, j=0..7
        f32x4 w[8];
        #pragma unroll
        for (int j = 0; j < 8; ++j)
            w[j] = *reinterpret_cast<const f32x4*>(wt1_b + (hbase + 4 * j) * NV);

        #pragma unroll
        for (int j = 0; j < 8; ++j) {
            const int h = hbase + 4 * j;
            const float inv = s_inv[h];           // wave-uniform broadcast
            const float sm  = s_sm[h];
            const f32x4 o = w[j] * inv;
            __builtin_nontemporal_store(o,
                reinterpret_cast<f32x4*>(wt2_b + h * NV));
            ax = fmaf(w[j].x, sm, ax);
            ay = fmaf(w[j].y, sm, ay);
            az = fmaf(w[j].z, sm, az);
            aw = fmaf(w[j].w, sm, aw);
        }
    }

    // Reduce the 4 h-group partials via LDS; all 256 threads write one v each.
    s_red[hg][v4 + 0] = ax;
    s_red[hg][v4 + 1] = ay;
    s_red[hg][v4 + 2] = az;
    s_red[hg][v4 + 3] = aw;
    __syncthreads();

    const float sum = s_red[0][t] + s_red[1][t] + s_red[2][t] + s_red[3][t];
    b2[(size_t)b * NV + t] = b1v - sum;
}

extern "C" void kernel_launch(void* const* d_in, const int* in_sizes, int n_in,
                              void* d_out, int out_size, void* d_ws, size_t ws_size,
                              hipStream_t stream) {
    const float* b1   = (const float*)d_in[0];  // [B, NV]
    const float* wt1  = (const float*)d_in[1];  // [B, NH, NV]
    const float* muh2 = (const float*)d_in[2];  // [B, NH]
    const float* cov  = (const float*)d_in[3];  // [B, NH]

    // d_out = concat(b2 [B*NV], wt2 [B*NH*NV]) in reference return order.
    float* b2  = (float*)d_out;
    float* wt2 = (float*)d_out + (size_t)NB * NV;

    convert_params_kernel<<<NB, 256, 0, stream>>>(b1, wt1, muh2, cov, b2, wt2);
}

// Round 6
// 92.460 us; speedup vs baseline: 1.2665x; 1.0128x over previous
//
#include <hip/hip_runtime.h>

// ConvertParamsLayerFrom0: B=2048, NH=128, NV=256
//   inv = rsqrt(covh_diag2)                     [B,NH]
//   wt2[b,h,v] = wt1[b,h,v] * inv[b,h]          [B,NH,NV]
//   b2[b,v]    = b1[b,v] - sum_h wt1[b,h,v] * (inv[b,h]*muh2[b,h])   [B,NV]
//
// R5: 2-deep software pipeline — issue group g+1's 8 loads before consuming
// group g, so reads stay outstanding during the store burst. Cached loads
// (L3 partial residency), nontemporal stores (don't evict wt1 from L3).
// Floor: 543 MB @ 6.29 TB/s copy-ceiling ~= 86 us.

#define NB 2048
#define NH 128
#define NV 256

typedef float f32x4 __attribute__((ext_vector_type(4)));

__global__ __launch_bounds__(256, 4) void convert_params_kernel(
    const float* __restrict__ b1,    // [B, NV]
    const float* __restrict__ wt1,   // [B, NH, NV]
    const float* __restrict__ muh2,  // [B, NH]
    const float* __restrict__ cov,   // [B, NH]
    float* __restrict__ b2,          // [B, NV]
    float* __restrict__ wt2)         // [B, NH, NV]
{
    const int b = blockIdx.x;
    const int t = threadIdx.x;

    __shared__ float s_inv[NH];      // rsqrt(cov)
    __shared__ float s_sm[NH];       // rsqrt(cov) * muh2
    __shared__ float s_red[4][NV];   // cross-h-group partials (4 KiB)

    // Preload b1 (1 elem/thread, coalesced) — hides under main loop.
    const float b1v = b1[(size_t)b * NV + t];

    // Stage per-(b,h) scalars in LDS.
    if (t < NH) {
        float c   = cov[(size_t)b * NH + t];
        float inv = rsqrtf(c);
        s_inv[t] = inv;
        s_sm[t]  = inv * muh2[(size_t)b * NH + t];
    }
    __syncthreads();

    // Layout: 4 h-groups x 64 lanes; each lane owns a float4 of v.
    const int lane = t & 63;         // 0..63  -> v4 = lane*4
    const int hg   = t >> 6;         // 0..3
    const int v4   = lane * 4;

    const float* wt1_b = wt1 + (size_t)b * NH * NV + v4;
    float*       wt2_b = wt2 + (size_t)b * NH * NV + v4;

    float ax = 0.f, ay = 0.f, az = 0.f, aw = 0.f;

    // 32 h-rows per lane as 4 groups of 8; double-buffered so group g+1's
    // loads are in flight while group g's scale+store+fma executes.
    // g is compile-time constant under full unroll -> w[][] stays in VGPRs.
    f32x4 w[2][8];

    #pragma unroll
    for (int j = 0; j < 8; ++j)
        w[0][j] = *reinterpret_cast<const f32x4*>(wt1_b + (hg + 4 * j) * NV);

    #pragma unroll
    for (int g = 0; g < 4; ++g) {
        if (g < 3) {
            const int hnext = hg + 32 * (g + 1);
            #pragma unroll
            for (int j = 0; j < 8; ++j)
                w[(g + 1) & 1][j] =
                    *reinterpret_cast<const f32x4*>(wt1_b + (hnext + 4 * j) * NV);
        }
        const int hbase = hg + 32 * g;
        #pragma unroll
        for (int j = 0; j < 8; ++j) {
            const int h = hbase + 4 * j;
            const float inv = s_inv[h];           // wave-uniform broadcast
            const float sm  = s_sm[h];
            const f32x4 ww = w[g & 1][j];
            const f32x4 o = ww * inv;
            __builtin_nontemporal_store(o,
                reinterpret_cast<f32x4*>(wt2_b + h * NV));
            ax = fmaf(ww.x, sm, ax);
            ay = fmaf(ww.y, sm, ay);
            az = fmaf(ww.z, sm, az);
            aw = fmaf(ww.w, sm, aw);
        }
    }

    // Reduce the 4 h-group partials via LDS; all 256 threads write one v each.
    s_red[hg][v4 + 0] = ax;
    s_red[hg][v4 + 1] = ay;
    s_red[hg][v4 + 2] = az;
    s_red[hg][v4 + 3] = aw;
    __syncthreads();

    const float sum = s_red[0][t] + s_red[1][t] + s_red[2][t] + s_red[3][t];
    b2[(size_t)b * NV + t] = b1v - sum;
}

extern "C" void kernel_launch(void* const* d_in, const int* in_sizes, int n_in,
                              void* d_out, int out_size, void* d_ws, size_t ws_size,
                              hipStream_t stream) {
    const float* b1   = (const float*)d_in[0];  // [B, NV]
    const float* wt1  = (const float*)d_in[1];  // [B, NH, NV]
    const float* muh2 = (const float*)d_in[2];  // [B, NH]
    const float* cov  = (const float*)d_in[3];  // [B, NH]

    // d_out = concat(b2 [B*NV], wt2 [B*NH*NV]) in reference return order.
    float* b2  = (float*)d_out;
    float* wt2 = (float*)d_out + (size_t)NB * NV;

    convert_params_kernel<<<NB, 256, 0, stream>>>(b1, wt1, muh2, cov, b2, wt2);
}